// Round 1
// baseline (74.401 us; speedup 1.0000x reference)
//
#include <hip/hip_runtime.h>

#define HDIM 256
#define SEQ 2048
#define TPOS 64

typedef _Float16 half8_t __attribute__((ext_vector_type(8)));
typedef float floatx16 __attribute__((ext_vector_type(16)));

#define U_PITCH 1024                           // bytes per U row (256 f32)
#define H_PITCH 512                            // bytes per h/x row (256 f16)
#define U_ROWS 79                              // 64 positions + 15 halo
#define H0_OFF (U_ROWS * U_PITCH)              // 80896
#define H1_OFF (H0_OFF + 64 * H_PITCH)         // 113664
#define LDS_BYTES (H0_OFF + 2 * 64 * H_PITCH)  // 146432 <= 160K

static __device__ __forceinline__ float exp2f_fast(float x) {
  float r; asm("v_exp_f32 %0, %1" : "=v"(r) : "v"(x)); return r;
}
static __device__ __forceinline__ float rcpf_fast(float x) {
  float r; asm("v_rcp_f32 %0, %1" : "=v"(r) : "v"(x)); return r;
}
static __device__ __forceinline__ float tanhf_fast(float x) {
  // tanh(x) = 1 - 2/(exp2(2*log2(e)*x) + 1); saturates correctly at +-inf
  float e = exp2f_fast(x * 2.8853900817779268f);
  return 1.0f - 2.0f * rcpf_fast(e + 1.0f);
}
static __device__ __forceinline__ unsigned pkh(float a, float b) {
  return __builtin_bit_cast(unsigned, __builtin_amdgcn_cvt_pkrtz(a, b));
}

// Wave w (0..7): jgroup = w>>1 owns output cols [64*jgroup, 64*jgroup+64),
//                pt = w&1 owns positions [32*pt, 32*pt+32) of the 64-pos tile.
// MFMA orientation: D[j][p] = sum_k W[j][k] * h[p][k]  (A = W rows, B = h^T).
// A-frag: lane holds A[l&31][(l>>5)*8 + i];  B-frag: B[(l>>5)*8+i][l&31];
// C/D:    col = l&31 (=p), row j_local = (r&3) + 8*(r>>2) + 4*(l>>5).
__global__ __launch_bounds__(512, 2) void winrnn_kernel(
    const float* __restrict__ x, const float* __restrict__ W_ih,
    const float* __restrict__ W_hh, const float* __restrict__ b_ih,
    const float* __restrict__ b_hh, float* __restrict__ out) {
  extern __shared__ char smem[];
  const int tid = threadIdx.x;
  const int w = tid >> 6;
  const int lane = tid & 63;
  const int l31 = lane & 31;
  const int hi = lane >> 5;

  const int wg = blockIdx.x;
  const int batch = wg >> 5;
  const int t0 = (wg & 31) * TPOS;
  const float* xb = x + (size_t)batch * SEQ * HDIM;

  const int jgroup = w >> 1;
  const int pt = w & 1;
  const int jbase = jgroup * 64;
  const int p_loc = pt * 32 + l31;

  // ---- stage x tile rows 0..78 (left halo of 15 zero-padded), rows 79..95
  // zero-filled, as f16 in LDS (h-buffer region), XOR-swizzled ----
  {
    char* xl = smem + H0_OFF;
#pragma unroll
    for (int it = 0; it < 12; ++it) {
      int idx = tid + it * 512;          // 96 rows * 64 float4-chunks
      int row = idx >> 6;
      int c4 = idx & 63;
      int xi = t0 - 15 + row;            // x index for this U row
      float4 v = make_float4(0.f, 0.f, 0.f, 0.f);
      if (row < U_ROWS && xi >= 0)
        v = *reinterpret_cast<const float4*>(xb + (size_t)xi * HDIM + c4 * 4);
      uint2 u;
      u.x = pkh(v.x, v.y);
      u.y = pkh(v.z, v.w);
      *reinterpret_cast<uint2*>(xl + row * H_PITCH + ((c4 * 8) ^ ((row & 31) << 4))) = u;
    }
  }

  // ---- W_ih fragments into registers (f32 -> f16) ----
  half8_t Wf[2][16];
#pragma unroll
  for (int jt = 0; jt < 2; ++jt)
#pragma unroll
    for (int kt = 0; kt < 16; ++kt) {
      const float* wp = W_ih + (size_t)(jbase + jt * 32 + l31) * HDIM + kt * 16 + hi * 8;
      float4 a = *reinterpret_cast<const float4*>(wp);
      float4 b = *reinterpret_cast<const float4*>(wp + 4);
      uint4 uu;
      uu.x = pkh(a.x, a.y); uu.y = pkh(a.z, a.w);
      uu.z = pkh(b.x, b.y); uu.w = pkh(b.z, b.w);
      Wf[jt][kt] = __builtin_bit_cast(half8_t, uu);
    }

  // ---- bias (b_ih + b_hh) in D-fragment layout ----
  float4 biasf[2][4];
#pragma unroll
  for (int jt = 0; jt < 2; ++jt)
#pragma unroll
    for (int g = 0; g < 4; ++g) {
      int j0 = jbase + jt * 32 + g * 8 + hi * 4;
      float4 bi = *reinterpret_cast<const float4*>(b_ih + j0);
      float4 bh = *reinterpret_cast<const float4*>(b_hh + j0);
      biasf[jt][g] = make_float4(bi.x + bh.x, bi.y + bh.y, bi.z + bh.z, bi.w + bh.w);
    }

  __syncthreads();

  // ---- U = x @ W_ih^T + bias  (fp32, stored swizzled in LDS) ----
  {
    const char* xl = smem + H0_OFF;
    char* Ul = smem;
    int nps = (pt == 0) ? 2 : 1;       // pt0 waves do row-tiles {0,2}, pt1 does {1}
    for (int s = 0; s < nps; ++s) {
      int prow = (pt + s * 2) * 32 + l31;
      floatx16 acc0, acc1;
#pragma unroll
      for (int g = 0; g < 4; ++g) {
        acc0[4*g+0] = biasf[0][g].x; acc0[4*g+1] = biasf[0][g].y;
        acc0[4*g+2] = biasf[0][g].z; acc0[4*g+3] = biasf[0][g].w;
        acc1[4*g+0] = biasf[1][g].x; acc1[4*g+1] = biasf[1][g].y;
        acc1[4*g+2] = biasf[1][g].z; acc1[4*g+3] = biasf[1][g].w;
      }
#pragma unroll
      for (int kt = 0; kt < 16; ++kt) {
        half8_t xB = *reinterpret_cast<const half8_t*>(
            xl + prow * H_PITCH + ((kt * 32 + hi * 16) ^ ((prow & 31) << 4)));
        acc0 = __builtin_amdgcn_mfma_f32_32x32x16_f16(Wf[0][kt], xB, acc0, 0, 0, 0);
        acc1 = __builtin_amdgcn_mfma_f32_32x32x16_f16(Wf[1][kt], xB, acc1, 0, 0, 0);
      }
      if (prow < U_ROWS) {
#pragma unroll
        for (int jt = 0; jt < 2; ++jt)
#pragma unroll
          for (int g = 0; g < 4; ++g) {
            int j0 = jbase + jt * 32 + g * 8 + hi * 4;
            float4 st;
            const floatx16& ac = jt ? acc1 : acc0;
            st.x = ac[4*g+0]; st.y = ac[4*g+1]; st.z = ac[4*g+2]; st.w = ac[4*g+3];
            *reinterpret_cast<float4*>(Ul + prow * U_PITCH + ((j0 * 4) ^ ((prow & 31) << 4))) = st;
          }
      }
    }
  }

  // ---- reload Wf with W_hh ----
#pragma unroll
  for (int jt = 0; jt < 2; ++jt)
#pragma unroll
    for (int kt = 0; kt < 16; ++kt) {
      const float* wp = W_hh + (size_t)(jbase + jt * 32 + l31) * HDIM + kt * 16 + hi * 8;
      float4 a = *reinterpret_cast<const float4*>(wp);
      float4 b = *reinterpret_cast<const float4*>(wp + 4);
      uint4 uu;
      uu.x = pkh(a.x, a.y); uu.y = pkh(a.z, a.w);
      uu.z = pkh(b.x, b.y); uu.w = pkh(b.z, b.w);
      Wf[jt][kt] = __builtin_bit_cast(half8_t, uu);
    }

  __syncthreads();

  // ---- 16-step windowed recurrence; h double-buffered in LDS ----
  const char* Ul = smem;
  char* hb0 = smem + H0_OFF;
  char* hb1 = smem + H1_OFF;
  float* outp = out + ((size_t)batch * SEQ + t0 + p_loc) * HDIM;
  const int hswz = (p_loc & 31) << 4;

  for (int k = 0; k < 16; ++k) {
    floatx16 acc0, acc1;
    int urow = p_loc + k;
    int uswz = (urow & 31) << 4;
#pragma unroll
    for (int g = 0; g < 4; ++g) {
      int j00 = (jbase + g * 8 + hi * 4) * 4;
      float4 u0 = *reinterpret_cast<const float4*>(Ul + urow * U_PITCH + (j00 ^ uswz));
      float4 u1 = *reinterpret_cast<const float4*>(Ul + urow * U_PITCH + ((j00 + 128) ^ uswz));
      acc0[4*g+0] = u0.x; acc0[4*g+1] = u0.y; acc0[4*g+2] = u0.z; acc0[4*g+3] = u0.w;
      acc1[4*g+0] = u1.x; acc1[4*g+1] = u1.y; acc1[4*g+2] = u1.z; acc1[4*g+3] = u1.w;
    }
    if (k > 0) {
      const char* hr = ((k & 1) ? hb0 : hb1);   // buffer written by step k-1
#pragma unroll
      for (int kt = 0; kt < 16; ++kt) {
        half8_t hB = *reinterpret_cast<const half8_t*>(
            hr + p_loc * H_PITCH + ((kt * 32 + hi * 16) ^ hswz));
        acc0 = __builtin_amdgcn_mfma_f32_32x32x16_f16(Wf[0][kt], hB, acc0, 0, 0, 0);
        acc1 = __builtin_amdgcn_mfma_f32_32x32x16_f16(Wf[1][kt], hB, acc1, 0, 0, 0);
      }
    }
    if (k < 15) {
      char* hw = ((k & 1) ? hb1 : hb0);
#pragma unroll
      for (int jt = 0; jt < 2; ++jt) {
        const floatx16& ac = jt ? acc1 : acc0;
#pragma unroll
        for (int g = 0; g < 4; ++g) {
          float ta = tanhf_fast(ac[4*g+0]);
          float tb = tanhf_fast(ac[4*g+1]);
          float tc = tanhf_fast(ac[4*g+2]);
          float td = tanhf_fast(ac[4*g+3]);
          uint2 u; u.x = pkh(ta, tb); u.y = pkh(tc, td);
          int jb = (jbase + jt * 32 + g * 8 + hi * 4) * 2;
          *reinterpret_cast<uint2*>(hw + p_loc * H_PITCH + (jb ^ hswz)) = u;
        }
      }
    } else {
#pragma unroll
      for (int jt = 0; jt < 2; ++jt) {
        const floatx16& ac = jt ? acc1 : acc0;
#pragma unroll
        for (int g = 0; g < 4; ++g) {
          float4 st;
          st.x = tanhf_fast(ac[4*g+0]); st.y = tanhf_fast(ac[4*g+1]);
          st.z = tanhf_fast(ac[4*g+2]); st.w = tanhf_fast(ac[4*g+3]);
          *reinterpret_cast<float4*>(outp + jbase + jt * 32 + g * 8 + hi * 4) = st;
        }
      }
    }
    __syncthreads();
  }
}

extern "C" void kernel_launch(void* const* d_in, const int* in_sizes, int n_in,
                              void* d_out, int out_size, void* d_ws, size_t ws_size,
                              hipStream_t stream) {
  const float* x    = (const float*)d_in[0];
  const float* W_ih = (const float*)d_in[1];
  const float* W_hh = (const float*)d_in[2];
  const float* b_ih = (const float*)d_in[3];
  const float* b_hh = (const float*)d_in[4];
  float* out = (float*)d_out;
  static_assert(LDS_BYTES <= 160 * 1024, "LDS budget");
  hipFuncSetAttribute(reinterpret_cast<const void*>(winrnn_kernel),
                      hipFuncAttributeMaxDynamicSharedMemorySize, LDS_BYTES);
  winrnn_kernel<<<dim3(256), dim3(512), LDS_BYTES, stream>>>(x, W_ih, W_hh, b_ih, b_hh, out);
}

// Round 2
// 73.370 us; speedup vs baseline: 1.0141x; 1.0141x over previous
//
#include <hip/hip_runtime.h>

#define HDIM 256
#define SEQ 2048
#define TPOS 32

typedef _Float16 half8_t __attribute__((ext_vector_type(8)));
typedef float floatx16 __attribute__((ext_vector_type(16)));

#define U_PITCH 1024                           // bytes per U row (256 f32)
#define H_PITCH 512                            // bytes per h/x row (256 f16)
#define U_ROWS 47                              // 32 positions + 15 halo
#define H0_OFF (U_ROWS * U_PITCH)              // 48128
#define H1_OFF (H0_OFF + 32 * H_PITCH)         // 64512
#define LDS_BYTES (H0_OFF + 2 * 32 * H_PITCH)  // 80896 -> 2 WGs/CU (161792 <= 163840)

static __device__ __forceinline__ float exp2f_fast(float x) {
  float r; asm("v_exp_f32 %0, %1" : "=v"(r) : "v"(x)); return r;
}
static __device__ __forceinline__ float rcpf_fast(float x) {
  float r; asm("v_rcp_f32 %0, %1" : "=v"(r) : "v"(x)); return r;
}
static __device__ __forceinline__ float tanhf_fast(float x) {
  // tanh(x) = 1 - 2/(exp2(2*log2(e)*x) + 1); saturates correctly at +-inf
  float e = exp2f_fast(x * 2.8853900817779268f);
  return 1.0f - 2.0f * rcpf_fast(e + 1.0f);
}
static __device__ __forceinline__ unsigned pkh(float a, float b) {
  return __builtin_bit_cast(unsigned, __builtin_amdgcn_cvt_pkrtz(a, b));
}

// 4 waves/WG; wave w owns output cols [64*w, 64*w+64) for all 32 positions.
// MFMA orientation: D[j][p] = sum_k W[j][k] * h[p][k]  (A = W rows, B = h^T).
// A-frag: lane holds A[l&31][(l>>5)*8 + i];  B-frag: B[(l>>5)*8+i][l&31];
// C/D:    col = l&31 (=p), row j_local = (r&3) + 8*(r>>2) + 4*(l>>5).
__global__ __launch_bounds__(256, 2) void winrnn_kernel(
    const float* __restrict__ x, const float* __restrict__ W_ih,
    const float* __restrict__ W_hh, const float* __restrict__ b_ih,
    const float* __restrict__ b_hh, float* __restrict__ out) {
  extern __shared__ char smem[];
  const int tid = threadIdx.x;
  const int w = tid >> 6;
  const int lane = tid & 63;
  const int l31 = lane & 31;
  const int hi = lane >> 5;

  const int wg = blockIdx.x;
  const int batch = wg >> 6;                 // 64 tiles per batch row
  const int t0 = (wg & 63) * TPOS;
  const float* xb = x + (size_t)batch * SEQ * HDIM;

  const int jbase = w * 64;
  const int p_loc = l31;
  const int hswz = l31 << 4;

  // ---- stage x rows [t0-15, t0+32) as f16 (rows 47..63 zero), swizzled,
  //      into the h-buffer region ----
  {
    char* xl = smem + H0_OFF;
#pragma unroll
    for (int it = 0; it < 16; ++it) {
      int idx = tid + it * 256;              // 64 rows * 64 float4-chunks
      int row = idx >> 6;
      int c4 = idx & 63;
      int xi = t0 - 15 + row;
      float4 v = make_float4(0.f, 0.f, 0.f, 0.f);
      if (row < U_ROWS && xi >= 0)
        v = *reinterpret_cast<const float4*>(xb + (size_t)xi * HDIM + c4 * 4);
      uint2 u;
      u.x = pkh(v.x, v.y);
      u.y = pkh(v.z, v.w);
      *reinterpret_cast<uint2*>(xl + row * H_PITCH + ((c4 * 8) ^ ((row & 31) << 4))) = u;
    }
  }

  // ---- W_ih fragments into registers (f32 -> f16) ----
  half8_t Wf[2][16];
#pragma unroll
  for (int jt = 0; jt < 2; ++jt)
#pragma unroll
    for (int kt = 0; kt < 16; ++kt) {
      const float* wp = W_ih + (size_t)(jbase + jt * 32 + l31) * HDIM + kt * 16 + hi * 8;
      float4 a = *reinterpret_cast<const float4*>(wp);
      float4 b = *reinterpret_cast<const float4*>(wp + 4);
      uint4 uu;
      uu.x = pkh(a.x, a.y); uu.y = pkh(a.z, a.w);
      uu.z = pkh(b.x, b.y); uu.w = pkh(b.z, b.w);
      Wf[jt][kt] = __builtin_bit_cast(half8_t, uu);
    }

  // ---- bias (b_ih + b_hh) in D-fragment layout ----
  float4 biasf[2][4];
#pragma unroll
  for (int jt = 0; jt < 2; ++jt)
#pragma unroll
    for (int g = 0; g < 4; ++g) {
      int j0 = jbase + jt * 32 + g * 8 + hi * 4;
      float4 bi = *reinterpret_cast<const float4*>(b_ih + j0);
      float4 bh = *reinterpret_cast<const float4*>(b_hh + j0);
      biasf[jt][g] = make_float4(bi.x + bh.x, bi.y + bh.y, bi.z + bh.z, bi.w + bh.w);
    }

  __syncthreads();

  // ---- U = x @ W_ih^T + bias (fp32, swizzled LDS); 2 row-tiles per wave ----
  {
    const char* xl = smem + H0_OFF;
    char* Ul = smem;
#pragma unroll
    for (int s = 0; s < 2; ++s) {
      int prow = s * 32 + l31;
      floatx16 acc0, acc1;
#pragma unroll
      for (int g = 0; g < 4; ++g) {
        acc0[4*g+0] = biasf[0][g].x; acc0[4*g+1] = biasf[0][g].y;
        acc0[4*g+2] = biasf[0][g].z; acc0[4*g+3] = biasf[0][g].w;
        acc1[4*g+0] = biasf[1][g].x; acc1[4*g+1] = biasf[1][g].y;
        acc1[4*g+2] = biasf[1][g].z; acc1[4*g+3] = biasf[1][g].w;
      }
#pragma unroll
      for (int kt = 0; kt < 16; ++kt) {
        half8_t xB = *reinterpret_cast<const half8_t*>(
            xl + prow * H_PITCH + ((kt * 32 + hi * 16) ^ ((prow & 31) << 4)));
        acc0 = __builtin_amdgcn_mfma_f32_32x32x16_f16(Wf[0][kt], xB, acc0, 0, 0, 0);
        acc1 = __builtin_amdgcn_mfma_f32_32x32x16_f16(Wf[1][kt], xB, acc1, 0, 0, 0);
      }
      if (prow < U_ROWS) {
#pragma unroll
        for (int jt = 0; jt < 2; ++jt)
#pragma unroll
          for (int g = 0; g < 4; ++g) {
            int j0 = jbase + jt * 32 + g * 8 + hi * 4;
            float4 st;
            const floatx16& ac = jt ? acc1 : acc0;
            st.x = ac[4*g+0]; st.y = ac[4*g+1]; st.z = ac[4*g+2]; st.w = ac[4*g+3];
            *reinterpret_cast<float4*>(Ul + prow * U_PITCH + ((j0 * 4) ^ ((prow & 31) << 4))) = st;
          }
      }
    }
  }

  // ---- reload Wf with W_hh ----
#pragma unroll
  for (int jt = 0; jt < 2; ++jt)
#pragma unroll
    for (int kt = 0; kt < 16; ++kt) {
      const float* wp = W_hh + (size_t)(jbase + jt * 32 + l31) * HDIM + kt * 16 + hi * 8;
      float4 a = *reinterpret_cast<const float4*>(wp);
      float4 b = *reinterpret_cast<const float4*>(wp + 4);
      uint4 uu;
      uu.x = pkh(a.x, a.y); uu.y = pkh(a.z, a.w);
      uu.z = pkh(b.x, b.y); uu.w = pkh(b.z, b.w);
      Wf[jt][kt] = __builtin_bit_cast(half8_t, uu);
    }

  __syncthreads();

  // ---- 16-step windowed recurrence; h double-buffered in LDS ----
  const char* Ul = smem;
  char* hb0 = smem + H0_OFF;
  char* hb1 = smem + H1_OFF;

  floatx16 acc0, acc1;
  for (int k = 0; k < 16; ++k) {
    int urow = p_loc + k;
    int uswz = (urow & 31) << 4;
#pragma unroll
    for (int g = 0; g < 4; ++g) {
      int j00 = (jbase + g * 8 + hi * 4) * 4;
      float4 u0 = *reinterpret_cast<const float4*>(Ul + urow * U_PITCH + (j00 ^ uswz));
      float4 u1 = *reinterpret_cast<const float4*>(Ul + urow * U_PITCH + ((j00 + 128) ^ uswz));
      acc0[4*g+0] = u0.x; acc0[4*g+1] = u0.y; acc0[4*g+2] = u0.z; acc0[4*g+3] = u0.w;
      acc1[4*g+0] = u1.x; acc1[4*g+1] = u1.y; acc1[4*g+2] = u1.z; acc1[4*g+3] = u1.w;
    }
    if (k > 0) {
      const char* hr = ((k & 1) ? hb0 : hb1);   // buffer written by step k-1
#pragma unroll
      for (int kt = 0; kt < 16; ++kt) {
        half8_t hB = *reinterpret_cast<const half8_t*>(
            hr + p_loc * H_PITCH + ((kt * 32 + hi * 16) ^ hswz));
        acc0 = __builtin_amdgcn_mfma_f32_32x32x16_f16(Wf[0][kt], hB, acc0, 0, 0, 0);
        acc1 = __builtin_amdgcn_mfma_f32_32x32x16_f16(Wf[1][kt], hB, acc1, 0, 0, 0);
      }
    }
    if (k < 15) {
      char* hw = ((k & 1) ? hb1 : hb0);
#pragma unroll
      for (int jt = 0; jt < 2; ++jt) {
        const floatx16& ac = jt ? acc1 : acc0;
#pragma unroll
        for (int g = 0; g < 4; ++g) {
          float ta = tanhf_fast(ac[4*g+0]);
          float tb = tanhf_fast(ac[4*g+1]);
          float tc = tanhf_fast(ac[4*g+2]);
          float td = tanhf_fast(ac[4*g+3]);
          uint2 u; u.x = pkh(ta, tb); u.y = pkh(tc, td);
          int jb = (jbase + jt * 32 + g * 8 + hi * 4) * 2;
          *reinterpret_cast<uint2*>(hw + p_loc * H_PITCH + (jb ^ hswz)) = u;
        }
      }
      __syncthreads();
    }
  }

  // ---- epilogue: final tanh -> f32 staged in LDS (h region) -> coalesced out
  __syncthreads();   // all step-15 reads of hb0 complete before overwrite
  {
    char* ol = smem + H0_OFF;                 // 32 rows x 1024 B
    const int oswz = (p_loc & 31) << 4;
#pragma unroll
    for (int jt = 0; jt < 2; ++jt) {
      const floatx16& ac = jt ? acc1 : acc0;
#pragma unroll
      for (int g = 0; g < 4; ++g) {
        float4 st;
        st.x = tanhf_fast(ac[4*g+0]); st.y = tanhf_fast(ac[4*g+1]);
        st.z = tanhf_fast(ac[4*g+2]); st.w = tanhf_fast(ac[4*g+3]);
        int jb = (jbase + jt * 32 + g * 8 + hi * 4) * 4;
        *reinterpret_cast<float4*>(ol + p_loc * 1024 + (jb ^ oswz)) = st;
      }
    }
  }
  __syncthreads();
  {
    const char* ol = smem + H0_OFF;
    float* ob = out + ((size_t)batch * SEQ + t0) * HDIM;
#pragma unroll
    for (int it = 0; it < 8; ++it) {
      int idx = tid + it * 256;               // 32 rows * 64 chunks
      int row = idx >> 6;
      int c = idx & 63;
      float4 v = *reinterpret_cast<const float4*>(
          ol + row * 1024 + ((c * 16) ^ ((row & 31) << 4)));
      *reinterpret_cast<float4*>(ob + (size_t)row * HDIM + c * 4) = v;
    }
  }
}

extern "C" void kernel_launch(void* const* d_in, const int* in_sizes, int n_in,
                              void* d_out, int out_size, void* d_ws, size_t ws_size,
                              hipStream_t stream) {
  const float* x    = (const float*)d_in[0];
  const float* W_ih = (const float*)d_in[1];
  const float* W_hh = (const float*)d_in[2];
  const float* b_ih = (const float*)d_in[3];
  const float* b_hh = (const float*)d_in[4];
  float* out = (float*)d_out;
  static_assert(2 * LDS_BYTES <= 160 * 1024, "need 2 WGs/CU");
  hipFuncSetAttribute(reinterpret_cast<const void*>(winrnn_kernel),
                      hipFuncAttributeMaxDynamicSharedMemorySize, LDS_BYTES);
  winrnn_kernel<<<dim3(512), dim3(256), LDS_BYTES, stream>>>(x, W_ih, W_hh, b_ih, b_hh, out);
}